// Round 10
// baseline (214.527 us; speedup 1.0000x reference)
//
#include <hip/hip_runtime.h>

#define HALO 10
#define NIMG 48                 // 16 batch * 3 channels

// Gaussian(sigma=1.5, 11 taps), normalized (computed offline in double).
#define GWLIST { 0.0010284f, 0.0075987f, 0.0360008f, 0.1093607f, 0.2130056f, \
                 0.2660117f, 0.2130056f, 0.1093607f, 0.0360008f, 0.0075987f, 0.0010284f }

// ======================= MFMA kernel (scales 0,1) ==========================
// fp16 pitches padded to 56 halves (112 B -> bank-stride 28, gcd(28,32)=4 ->
// 2-way aliasing = free).
// R6: two tiles per block. R7: sched_barrier failed to pin (VGPR stayed 44,
// MachineSink moved loads to use). R8: inline-asm loads; container died
// (cause unknown) AND audit showed __syncthreads at barrier B emits
// vmcnt(0), draining the prefetch anyway.
// R9: (1) VOLATILE vector loads -- MachineSink cannot move volatile memory
// ops, and volatile <4 x float> emits one global_load_dwordx4; (2) barrier B
// softened to lgkmcnt(0)+s_barrier (LDS ordering only) so the prefetch
// survives it; compiler inserts the precise vmcnt wait at the use.
#define PP   56                 // stage-1 plane pitch (fp16 units)
#define PSZ  (48 * 56)          // plane size = 2688 fp16
#define HT0  (2 * PSZ)          // h_T region base = 5376 fp16
#define HTP  56                 // h_T pitch along r (fp16 units)
#define HTSZ (32 * 56)          // per-quantity h_T = 1792 fp16
#define WT0  (HT0 + 5 * HTSZ)   // wfrag table offset = 14336 fp16
#define LDSH (WT0 + 64 * 8)     // 14848 fp16 = 29696 B -> 5 blocks/CU

typedef _Float16 half8 __attribute__((ext_vector_type(8)));
typedef _Float16 half4 __attribute__((ext_vector_type(4)));
typedef float    floatx4 __attribute__((ext_vector_type(4)));

struct JR { floatx4 al, ah, bl, bh; };  // one staging job: 8 a-floats, 8 b-floats

// Guarded/generic load (edge tiles, and tile-0 where there is nothing to
// hide under anyway).
__device__ __forceinline__ void issue_job(const float* __restrict__ a,
                                          const float* __restrict__ b,
                                          int H, int W, int gx0, int gy0,
                                          int e, bool fast, JR& r)
{
    int rr = e / 6, c8 = e - rr * 6;
    if (fast) {
        const float* pa = a + (size_t)(gy0 + rr) * W + gx0 + c8 * 8;
        const float* pb = b + (size_t)(gy0 + rr) * W + gx0 + c8 * 8;
        r.al = *(const floatx4*)pa;      r.ah = *(const floatx4*)(pa + 4);
        r.bl = *(const floatx4*)pb;      r.bh = *(const floatx4*)(pb + 4);
    } else {
        float fa[8], fb[8];
        int gy = gy0 + rr;
        #pragma unroll
        for (int i = 0; i < 8; ++i) {
            int gx = gx0 + c8 * 8 + i;
            bool ok = (gy < H) && (gx < W);
            size_t idx = (size_t)gy * W + gx;
            fa[i] = ok ? a[idx] : 0.f;
            fb[i] = ok ? b[idx] : 0.f;
        }
        #pragma unroll
        for (int i = 0; i < 4; ++i) {
            r.al[i] = fa[i];  r.ah[i] = fa[4 + i];
            r.bl[i] = fb[i];  r.bh[i] = fb[4 + i];
        }
    }
}

// PINNED prefetch via volatile loads: emitted exactly here (volatile memory
// ops cannot be sunk/duplicated); the vmcnt wait lands at the use.
__device__ __forceinline__ void issue_job_pinned(const float* __restrict__ a,
                                                 const float* __restrict__ b,
                                                 int W, int gx0, int gy0,
                                                 int e, JR& r)
{
    int rr = e / 6, c8 = e - rr * 6;
    const float* pa = a + (size_t)(gy0 + rr) * W + gx0 + c8 * 8;
    const float* pb = b + (size_t)(gy0 + rr) * W + gx0 + c8 * 8;
    r.al = *(volatile const floatx4*)pa;
    r.ah = *(volatile const floatx4*)(pa + 4);
    r.bl = *(volatile const floatx4*)pb;
    r.bh = *(volatile const floatx4*)(pb + 4);
}

__device__ __forceinline__ void store_job(_Float16* __restrict__ sm, int e, const JR& r)
{
    int rr = e / 6, c8 = e - rr * 6;
    float fa[8] = {r.al[0], r.al[1], r.al[2], r.al[3], r.ah[0], r.ah[1], r.ah[2], r.ah[3]};
    float fb[8] = {r.bl[0], r.bl[1], r.bl[2], r.bl[3], r.bh[0], r.bh[1], r.bh[2], r.bh[3]};
    half8 ha, hb;
    #pragma unroll
    for (int i = 0; i < 8; ++i) {
        ha[i] = (_Float16)fa[i];
        hb[i] = (_Float16)fb[i];
    }
    int o = rr * PP + c8 * 8;
    *(half8*)&sm[o]       = ha;
    *(half8*)&sm[o + PSZ] = hb;
}

// stage 2: h-conv via MFMA, branch-free per-position (R5 body, verified).
__device__ __forceinline__ void stage2(_Float16* __restrict__ sm, half8 wfrag,
                                       int lane, int wv)
{
    const int arow = (lane & 15) * PP + ((lane >> 4) << 3);
    const int crow = (lane & 15) * HTP + ((lane >> 4) << 2);
    #pragma unroll 2
    for (int p = wv; p < 6; p += 4) {
        int m0 = (p >> 1) << 4;
        int x0 = (p & 1) << 4;
        int fb_ = m0 * PP + x0 + arow;
        half8 ha  = *(const half8*)&sm[fb_];
        half8 hb  = *(const half8*)&sm[fb_ + PSZ];
        half8 faa = ha * ha;                  // == stored fp16 a*a
        half8 fbb = hb * hb;
        half8 fab = ha * hb;
        floatx4 zero = {0.f, 0.f, 0.f, 0.f};
        floatx4 c0 = __builtin_amdgcn_mfma_f32_16x16x32_f16(ha,  wfrag, zero, 0, 0, 0);
        floatx4 c1 = __builtin_amdgcn_mfma_f32_16x16x32_f16(hb,  wfrag, zero, 0, 0, 0);
        floatx4 c2 = __builtin_amdgcn_mfma_f32_16x16x32_f16(faa, wfrag, zero, 0, 0, 0);
        floatx4 c3 = __builtin_amdgcn_mfma_f32_16x16x32_f16(fbb, wfrag, zero, 0, 0, 0);
        floatx4 c4 = __builtin_amdgcn_mfma_f32_16x16x32_f16(fab, wfrag, zero, 0, 0, 0);
        int cb = HT0 + x0 * HTP + m0 + crow;
        half4 h0, h1, h2, h3, h4;
        #pragma unroll
        for (int i = 0; i < 4; ++i) {
            h0[i] = (_Float16)c0[i];
            h1[i] = (_Float16)c1[i];
            h2[i] = (_Float16)c2[i];
            h3[i] = (_Float16)c3[i];
            h4[i] = (_Float16)c4[i];
        }
        *(half4*)&sm[cb + 0 * HTSZ] = h0;
        *(half4*)&sm[cb + 1 * HTSZ] = h1;
        *(half4*)&sm[cb + 2 * HTSZ] = h2;
        *(half4*)&sm[cb + 3 * HTSZ] = h3;
        *(half4*)&sm[cb + 4 * HTSZ] = h4;
    }
}

// stage 3: v-conv via MFMA + SSIM (R5 body, verified).
__device__ __forceinline__ void stage3(const _Float16* __restrict__ sm, half8 wfrag,
                                       int lane, int wv, int H, int W,
                                       int gx0, int gy0,
                                       float& csSum, float& ssimSum)
{
    const int y0 = (wv >> 1) << 4;
    const int x0 = (wv & 1) << 4;
    const int brow = (lane & 15) * HTP + ((lane >> 4) << 3);
    floatx4 m[5];
    #pragma unroll
    for (int q = 0; q < 5; ++q) {
        half8 bfrag = *(const half8*)&sm[HT0 + q * HTSZ + x0 * HTP + y0 + brow];
        floatx4 c = {0.f, 0.f, 0.f, 0.f};
        m[q] = __builtin_amdgcn_mfma_f32_16x16x32_f16(wfrag, bfrag, c, 0, 0, 0);
    }
    const int OH = H - HALO, OW = W - HALO;
    const int gx  = gx0 + x0 + (lane & 15);
    const int gyb = gy0 + y0 + ((lane >> 4) << 2);
    const float C1 = 1e-4f;   // (0.01*1)^2
    const float C2 = 9e-4f;   // (0.03*1)^2
    csSum = 0.f; ssimSum = 0.f;
    if (gx < OW) {
        #pragma unroll
        for (int i = 0; i < 4; ++i) {
            int gy = gyb + i;
            if (gy < OH) {
                float mu1 = m[0][i], mu2 = m[1][i];
                float s1sq = m[2][i] - mu1 * mu1;
                float s2sq = m[3][i] - mu2 * mu2;
                float s12  = m[4][i] - mu1 * mu2;
                float denom = s1sq + s2sq + C2;
                float num   = 2.f * s12 + C2;
                float csv = num * __frcp_rn(denom);
                float ssv = csv * (2.f * mu1 * mu2 + C1) *
                            __frcp_rn(mu1 * mu1 + mu2 * mu2 + C1);
                csSum   += csv;
                ssimSum += ssv;
            }
        }
    }
}

// block reduction -> one partial slot (contains one __syncthreads).
__device__ __forceinline__ void block_reduce_store(float csSum, float ssimSum,
                                                   float* __restrict__ red,
                                                   int tid, int lane, int wv,
                                                   float2* __restrict__ partial,
                                                   int slot)
{
    #pragma unroll
    for (int off = 32; off > 0; off >>= 1) {
        csSum   += __shfl_down(csSum, off, 64);
        ssimSum += __shfl_down(ssimSum, off, 64);
    }
    if (lane == 0) {
        red[wv]     = csSum;
        red[8 + wv] = ssimSum;
    }
    __syncthreads();
    if (tid == 0) {
        float c = 0.f, s = 0.f;
        #pragma unroll
        for (int i = 0; i < 4; ++i) { c += red[i]; s += red[8 + i]; }
        partial[slot] = make_float2(c, s);
    }
}

// fused 2x2 avg-pool of one 32x32 tile (reads global, L2-hot after stage 1).
__device__ __forceinline__ void pool_tile(const float* __restrict__ a,
                                          const float* __restrict__ b,
                                          int H, int W, int gx0, int gy0, int z,
                                          float* __restrict__ poolA,
                                          float* __restrict__ poolB, int tid)
{
    if (tid < 128) {
        const int OH2 = H >> 1, OW2 = W >> 1;
        const int img = tid >> 6;            // 0 = A, 1 = B
        const int rem = tid & 63;
        const int pr  = rem >> 2;            // pooled row 0..15
        const int pq  = rem & 3;             // pooled float4-col 0..3
        const float* src = img ? b : a;
        float* dst = (img ? poolB : poolA) + (size_t)z * OH2 * OW2;
        size_t base = (size_t)(gy0 + 2 * pr) * W + gx0 + pq * 8;
        float4 r0 = *(const float4*)(src + base);
        float4 r1 = *(const float4*)(src + base + 4);
        float4 r2 = *(const float4*)(src + base + W);
        float4 r3 = *(const float4*)(src + base + W + 4);
        float4 o;
        o.x = 0.25f * (r0.x + r0.y + r2.x + r2.y);
        o.y = 0.25f * (r0.z + r0.w + r2.z + r2.w);
        o.z = 0.25f * (r1.x + r1.y + r3.x + r3.y);
        o.w = 0.25f * (r1.z + r1.w + r3.z + r3.w);
        *(float4*)(dst + (size_t)((gy0 >> 1) + pr) * OW2 + (gx0 >> 1) + pq * 4) = o;
    }
}

// Two adjacent tiles per block, software-pipelined; tile-1 prefetch is
// volatile (cannot be sunk) and SURVIVES barrier B (lgkmcnt-only barrier):
//  issue(t0) -> wfrag -> store(t0) -> A -> issue_pinned(t1) -> stage2(t0)
//  -> B[lgkm only] -> stage3(t0) -> store(t1)[vmcnt wait here] -> C ->
//  pool(t0) -> stage2(t1) -> E -> stage3(t1) -> combined reduce -> pool(t1)
// Hazard audit for softened B: stage2's LDS writes drained by lgkmcnt(0);
// all waves' plane READS (stage2) drained before any wave passes B, so
// planes(t1) writes (post-B, pre-C) are WAR-safe; h_T(t1) written post-C
// (full __syncthreads), read post-E. In-flight global prefetch is
// per-thread register data -- no cross-thread hazard at B.
template <bool FUSE>
__global__ __launch_bounds__(256, 5) void ssim_mfma_kernel(
    const float* __restrict__ A, const float* __restrict__ B,
    int H, int W, float2* __restrict__ partial,
    float* __restrict__ poolA, float* __restrict__ poolB)
{
    __shared__ __align__(16) _Float16 sm[LDSH];   // 29696 B
    __shared__ float red[16];

    const float w[11] = GWLIST;
    const int tid  = threadIdx.x;
    const int lane = tid & 63;
    const int wv   = tid >> 6;
    const int tx0  = blockIdx.x * 2;              // tile-pair column base
    const int gxA  = tx0 * 32;
    const int gxB  = gxA + 32;
    const int gy0  = blockIdx.y * 32;
    const int z    = blockIdx.z;
    const float* a = A + (size_t)z * H * W;
    const float* b = B + (size_t)z * H * W;

    const int slotP = (z * gridDim.y + blockIdx.y) * gridDim.x + blockIdx.x;

    const bool fastA = (gy0 + 48 <= H) && (gxA + 48 <= W);
    const bool fastB = (gy0 + 48 <= H) && (gxB + 48 <= W);
    const int  e0 = tid;                 // always < 288
    const int  e1 = tid + 256;           // valid for tid < 32
    const bool has2 = (tid < 32);

    // ---- tile-0 loads + wfrag table -------------------------------------
    JR j0, j1;
    issue_job(a, b, H, W, gxA, gy0, e0, fastA, j0);
    if (has2) issue_job(a, b, H, W, gxA, gy0, e1, fastA, j1);

    if (tid < 64) {
        int base = ((tid >> 4) << 3) - (tid & 15);
        half8 wf;
        #pragma unroll
        for (int i = 0; i < 8; ++i) {
            int j = base + i;
            float v = 0.f;
            #pragma unroll
            for (int J = 0; J < 11; ++J) v = (j == J) ? w[J] : v;
            wf[i] = (_Float16)v;
        }
        *(half8*)&sm[WT0 + tid * 8] = wf;
    }

    store_job(sm, e0, j0);
    if (has2) store_job(sm, e1, j1);
    __syncthreads();                               // A: planes(t0) ready

    const half8 wfrag = *(const half8*)&sm[WT0 + lane * 8];

    // ---- tile-1 prefetch, pinned (volatile); hides under stage2/3(t0) ---
    JR k0, k1;
    if (fastB) {
        issue_job_pinned(a, b, W, gxB, gy0, e0, k0);
        if (has2) issue_job_pinned(a, b, W, gxB, gy0, e1, k1);
    } else {
        issue_job(a, b, H, W, gxB, gy0, e0, false, k0);
        if (has2) issue_job(a, b, H, W, gxB, gy0, e1, false, k1);
    }

    stage2(sm, wfrag, lane, wv);                   // t0: planes -> h_T

    // B: LDS-only barrier -- does NOT drain vmcnt, prefetch stays in flight
    asm volatile("s_waitcnt lgkmcnt(0)\n\ts_barrier" ::: "memory");

    float cs0, ss0;
    stage3(sm, wfrag, lane, wv, H, W, gxA, gy0, cs0, ss0);

    store_job(sm, e0, k0);     // compiler inserts the precise vmcnt wait here
    if (has2) store_job(sm, e1, k1);
    __syncthreads();                               // C: planes(t1) ready

    if (FUSE) pool_tile(a, b, H, W, gxA, gy0, z, poolA, poolB, tid);

    stage2(sm, wfrag, lane, wv);                   // t1: planes -> h_T
    __syncthreads();                               // E: h_T(t1) ready

    float cs1, ss1;
    stage3(sm, wfrag, lane, wv, H, W, gxB, gy0, cs1, ss1);

    // combined reduction for both tiles -> one per-pair slot
    block_reduce_store(cs0 + cs1, ss0 + ss1, red, tid, lane, wv, partial, slotP);

    if (FUSE) pool_tile(a, b, H, W, gxB, gy0, z, poolA, poolB, tid);
}

// ================= exact fp32 scalar kernel (scales 2-4) ===================
#define TH   32
#define ROWS (TH + HALO)      // 42
#define HSTR 32
#define HQ   (ROWS * HSTR)    // 1344 floats

template <bool FUSE>
__global__ __launch_bounds__(256, 5) void ssim_scalar_kernel(
    const float* __restrict__ A, const float* __restrict__ B,
    int H, int W, float2* __restrict__ partial,
    float* __restrict__ poolA, float* __restrict__ poolB)
{
    __shared__ __align__(16) float lds[5 * HQ];   // 26880 B
    __shared__ float red[16];

    const float w[11] = GWLIST;

    const int tid = threadIdx.x;
    const int gx0 = blockIdx.x * 32;
    const int gy0 = blockIdx.y * TH;
    const int z   = blockIdx.z;
    const float* a = A + (size_t)z * H * W;
    const float* b = B + (size_t)z * H * W;

    const bool fast = (gy0 + ROWS <= H) && (gx0 + 44 <= W);
    for (int e = tid; e < ROWS * 8; e += 256) {
        int r = e >> 3, c0 = (e & 7) * 4;
        int gy = gy0 + r;
        float s1[4]  = {0.f, 0.f, 0.f, 0.f};
        float s2[4]  = {0.f, 0.f, 0.f, 0.f};
        float s11[4] = {0.f, 0.f, 0.f, 0.f};
        float s22[4] = {0.f, 0.f, 0.f, 0.f};
        float s12[4] = {0.f, 0.f, 0.f, 0.f};
        #pragma unroll
        for (int c = 0; c < 4; ++c) {
            float ea[4], eb[4];
            if (fast) {
                const float* pa = a + (size_t)gy * W + gx0 + c0 + 4 * c;
                const float* pb = b + (size_t)gy * W + gx0 + c0 + 4 * c;
                *(float4*)&ea[0] = *(const float4*)pa;
                *(float4*)&eb[0] = *(const float4*)pb;
            } else {
                #pragma unroll
                for (int t = 0; t < 4; ++t) {
                    int gx = gx0 + c0 + 4 * c + t;
                    bool ok = (gy < H) && (gx < W);
                    size_t idx = (size_t)gy * W + gx;
                    ea[t] = ok ? a[idx] : 0.f;
                    eb[t] = ok ? b[idx] : 0.f;
                }
            }
            #pragma unroll
            for (int mm = 0; mm < 4; ++mm) {
                const int i = 4 * c + mm;
                float va = ea[mm], vb = eb[mm];
                float vaa = va * va, vbb = vb * vb, vab = va * vb;
                #pragma unroll
                for (int k = 0; k < 4; ++k) {
                    const int j = i - k;
                    if (j >= 0 && j <= 10) {
                        float wj = w[j];
                        s1[k]  += wj * va;
                        s2[k]  += wj * vb;
                        s11[k] += wj * vaa;
                        s22[k] += wj * vbb;
                        s12[k] += wj * vab;
                    }
                }
            }
        }
        int hb = r * HSTR + c0;
        *(float4*)&lds[hb + 0 * HQ] = make_float4(s1[0],  s1[1],  s1[2],  s1[3]);
        *(float4*)&lds[hb + 1 * HQ] = make_float4(s2[0],  s2[1],  s2[2],  s2[3]);
        *(float4*)&lds[hb + 2 * HQ] = make_float4(s11[0], s11[1], s11[2], s11[3]);
        *(float4*)&lds[hb + 3 * HQ] = make_float4(s22[0], s22[1], s22[2], s22[3]);
        *(float4*)&lds[hb + 4 * HQ] = make_float4(s12[0], s12[1], s12[2], s12[3]);
    }
    __syncthreads();

    const float C1 = 1e-4f;
    const float C2 = 9e-4f;
    float csSum = 0.f, ssimSum = 0.f;
    {
        const int ox  = tid & 31;
        const int oy0 = (tid >> 5) * 4;
        float m[5][4];
        #pragma unroll
        for (int q = 0; q < 5; ++q) {
            const float* hq = &lds[q * HQ + oy0 * HSTR + ox];
            float win[14];
            #pragma unroll
            for (int i = 0; i < 14; ++i) win[i] = hq[i * HSTR];
            #pragma unroll
            for (int k = 0; k < 4; ++k) {
                float acc = 0.f;
                #pragma unroll
                for (int j = 0; j < 11; ++j) acc += w[j] * win[k + j];
                m[q][k] = acc;
            }
        }
        const int OH = H - HALO, OW = W - HALO;
        const int gx = gx0 + ox;
        #pragma unroll
        for (int k = 0; k < 4; ++k) {
            int gy = gy0 + oy0 + k;
            if (gy < OH && gx < OW) {
                float mu1 = m[0][k], mu2 = m[1][k];
                float s1sq = m[2][k] - mu1 * mu1;
                float s2sq = m[3][k] - mu2 * mu2;
                float s12  = m[4][k] - mu1 * mu2;
                float denom  = s1sq + s2sq + C2;
                float num_cs = 2.f * s12 + C2;
                float csv = num_cs * __frcp_rn(denom);
                float ssv = csv * (2.f * mu1 * mu2 + C1) *
                            __frcp_rn(mu1 * mu1 + mu2 * mu2 + C1);
                csSum   += csv;
                ssimSum += ssv;
            }
        }
    }

    #pragma unroll
    for (int off = 32; off > 0; off >>= 1) {
        csSum   += __shfl_down(csSum, off, 64);
        ssimSum += __shfl_down(ssimSum, off, 64);
    }
    int wave = tid >> 6, lane = tid & 63;
    if (lane == 0) {
        red[wave]     = csSum;
        red[8 + wave] = ssimSum;
    }
    __syncthreads();
    if (tid == 0) {
        float c = 0.f, s = 0.f;
        #pragma unroll
        for (int i = 0; i < 4; ++i) { c += red[i]; s += red[8 + i]; }
        int slot = (z * gridDim.y + blockIdx.y) * gridDim.x + blockIdx.x;
        partial[slot] = make_float2(c, s);
    }

    if (FUSE && tid < 128) {
        const int OH2 = H >> 1, OW2 = W >> 1;
        const int img = tid >> 6;
        const int rem = tid & 63;
        const int pr  = rem >> 2;
        const int pq  = rem & 3;
        const float* src = img ? b : a;
        float* dst = (img ? poolB : poolA) + (size_t)z * OH2 * OW2;
        size_t base = (size_t)(gy0 + 2 * pr) * W + gx0 + pq * 8;
        float4 r0 = *(const float4*)(src + base);
        float4 r1 = *(const float4*)(src + base + 4);
        float4 r2 = *(const float4*)(src + base + W);
        float4 r3 = *(const float4*)(src + base + W + 4);
        float4 o;
        o.x = 0.25f * (r0.x + r0.y + r2.x + r2.y);
        o.y = 0.25f * (r0.z + r0.w + r2.z + r2.w);
        o.z = 0.25f * (r1.x + r1.y + r3.x + r3.y);
        o.w = 0.25f * (r1.z + r1.w + r3.z + r3.w);
        *(float4*)(dst + (size_t)((gy0 >> 1) + pr) * OW2 + (gx0 >> 1) + pq * 4) = o;
    }
}

// ---------------------------------------------------------------------------
// Reduce all per-block partials (5 segments) and combine.
// Segments (per-pair slots for MFMA scales): s0 6144, s1 1536, s2 768,
// s3 192, s4 48 -> total 8688.
__global__ void final_kernel(const float2* __restrict__ partial, float* __restrict__ out) {
    __shared__ double red[8];
    __shared__ double resC[5], resS[5];
    const int segs[6] = {0, 6144, 7680, 8448, 8640, 8688};
    const int tid = threadIdx.x;
    for (int s = 0; s < 5; ++s) {
        double c = 0.0, v = 0.0;
        #pragma unroll 4
        for (int i = segs[s] + tid; i < segs[s + 1]; i += 256) {
            float2 p = partial[i];
            c += (double)p.x;
            v += (double)p.y;
        }
        #pragma unroll
        for (int off = 32; off > 0; off >>= 1) {
            c += __shfl_down(c, off, 64);
            v += __shfl_down(v, off, 64);
        }
        int wave = tid >> 6, lane = tid & 63;
        __syncthreads();
        if (lane == 0) { red[wave] = c; red[4 + wave] = v; }
        __syncthreads();
        if (tid == 0) {
            resC[s] = red[0] + red[1] + red[2] + red[3];
            resS[s] = red[4] + red[5] + red[6] + red[7];
        }
    }
    __syncthreads();
    if (tid == 0) {
        const double wgt[5] = {0.0448, 0.2856, 0.3001, 0.2363, 0.1333};
        double ms = 1.0;
        for (int s = 0; s < 5; ++s) {
            int Hs = 512 >> s;
            double cnt = (double)NIMG * (double)(Hs - 10) * (double)(Hs - 10);
            double cs = resC[s] / cnt;
            double sv = resS[s] / cnt;
            if (cs < 0.0) cs = 0.0;
            if (sv < 0.0) sv = 0.0;
            cs = (cs + 1.0) * 0.5;
            sv = (sv + 1.0) * 0.5;
            ms *= pow((s < 4) ? cs : sv, wgt[s]);
        }
        out[0] = (float)(1.0 - ms);
    }
}

// ---------------------------------------------------------------------------
extern "C" void kernel_launch(void* const* d_in, const int* in_sizes, int n_in,
                              void* d_out, int out_size, void* d_ws, size_t ws_size,
                              hipStream_t stream) {
    (void)in_sizes; (void)n_in; (void)out_size; (void)ws_size;
    const float* A0 = (const float*)d_in[0];
    const float* B0 = (const float*)d_in[1];
    float* out = (float*)d_out;

    char* ws = (char*)d_ws;
    float2* partial = (float2*)ws;             // 8688 float2 = 70 KB
    float* pyr = (float*)(ws + (1 << 18));     // 256 KB offset

    float* pa[5] = {nullptr, nullptr, nullptr, nullptr, nullptr};
    float* pb[5] = {nullptr, nullptr, nullptr, nullptr, nullptr};
    size_t off = 0;
    for (int s = 1; s <= 4; ++s) {
        int Hs = 512 >> s;
        size_t n = (size_t)NIMG * Hs * Hs;
        pa[s] = pyr + off; off += n;
        pb[s] = pyr + off; off += n;
    }

    const int segs[5] = {0, 6144, 7680, 8448, 8640};

    const float* curA = A0;
    const float* curB = B0;
    for (int s = 0; s < 5; ++s) {
        int Hs = 512 >> s;
        int g  = Hs >> 5;                      // tiles exactly cover image
        if (s < 2) {
            dim3 grid(g >> 1, g, NIMG);        // two tiles per block
            ssim_mfma_kernel<true><<<grid, 256, 0, stream>>>(
                curA, curB, Hs, Hs, partial + segs[s], pa[s + 1], pb[s + 1]);
            curA = pa[s + 1];
            curB = pb[s + 1];
        } else if (s < 4) {
            dim3 grid(g, g, NIMG);
            ssim_scalar_kernel<true><<<grid, 256, 0, stream>>>(
                curA, curB, Hs, Hs, partial + segs[s], pa[s + 1], pb[s + 1]);
            curA = pa[s + 1];
            curB = pb[s + 1];
        } else {
            dim3 grid(g, g, NIMG);
            ssim_scalar_kernel<false><<<grid, 256, 0, stream>>>(
                curA, curB, Hs, Hs, partial + segs[s], nullptr, nullptr);
        }
    }

    final_kernel<<<1, 256, 0, stream>>>(partial, out);
}

// Round 12
// 200.338 us; speedup vs baseline: 1.0708x; 1.0708x over previous
//
#include <hip/hip_runtime.h>

#define HALO 10
#define NIMG 48                 // 16 batch * 3 channels

// Gaussian(sigma=1.5, 11 taps), normalized (computed offline in double).
#define GWLIST { 0.0010284f, 0.0075987f, 0.0360008f, 0.1093607f, 0.2130056f, \
                 0.2660117f, 0.2130056f, 0.1093607f, 0.0360008f, 0.0075987f, 0.0010284f }

// ======================= MFMA kernel (scales 0,1) ==========================
// R6-R9 post-mortem: four attempts to pin a cross-tile global prefetch all
// failed (VGPR never moved off 44 -- compiler sinks loads or hoists their
// consumers; vmcnt waits land at issue). Arc closed.
// R10/R11: occupancy instead. h_T (17920B) and planes (10752B) ALIAS (R0's
// proven trick): stage2 computes all h-conv results into REGISTERS (10
// half4/thread), barrier, then writes h_T over the dead plane region.
// LDS = max(h_T, planes) + wfrag = 18944B -> 7 blocks/CU (was 5), +40%
// resident waves to hide the exposed latency via inter-block TLP.
// (R11 = byte-identical resubmission of R10: the container died on infra,
// not on this kernel -- it is vanilla HIP with verified math.)
// fp16 pitches padded to 56 halves (112B -> bank-stride 28, gcd(28,32)=4 ->
// 2-way aliasing = free; pitch must be multiple of 8 halves for b128).
#define PP   56                 // stage-1 plane pitch (fp16 units)
#define PSZ  (48 * 56)          // plane size = 2688 fp16
// h_T region base 0 (ALIASES planes); planes: a at [0,PSZ), b at [PSZ,2*PSZ)
#define HTP  56                 // h_T pitch along r (fp16 units)
#define HTSZ (32 * 56)          // per-quantity h_T = 1792 fp16
#define WT0  (5 * HTSZ)         // wfrag table offset = 8960 fp16
#define LDSH (WT0 + 64 * 8)     // 9472 fp16 = 18944 B -> 7 blocks/CU

typedef _Float16 half8 __attribute__((ext_vector_type(8)));
typedef _Float16 half4 __attribute__((ext_vector_type(4)));
typedef float    floatx4 __attribute__((ext_vector_type(4)));

// h-conv for one position p: read a,b fragments from planes, build the 5
// quantity fragments in-register (bit-identical fp16 products), 5 MFMAs,
// convert to half4. Results held in regs (out[] indexed only by unrolled
// constants -- stays in VGPRs).
__device__ __forceinline__ void hconv_pos(const _Float16* __restrict__ sm,
                                          half8 wfrag, int p, int arow,
                                          half4 out[5])
{
    int m0 = (p >> 1) << 4;
    int x0 = (p & 1) << 4;
    int fb_ = m0 * PP + x0 + arow;
    half8 ha  = *(const half8*)&sm[fb_];
    half8 hb  = *(const half8*)&sm[fb_ + PSZ];
    half8 faa = ha * ha;                  // == stored fp16 a*a
    half8 fbb = hb * hb;
    half8 fab = ha * hb;
    floatx4 zero = {0.f, 0.f, 0.f, 0.f};
    floatx4 c0 = __builtin_amdgcn_mfma_f32_16x16x32_f16(ha,  wfrag, zero, 0, 0, 0);
    floatx4 c1 = __builtin_amdgcn_mfma_f32_16x16x32_f16(hb,  wfrag, zero, 0, 0, 0);
    floatx4 c2 = __builtin_amdgcn_mfma_f32_16x16x32_f16(faa, wfrag, zero, 0, 0, 0);
    floatx4 c3 = __builtin_amdgcn_mfma_f32_16x16x32_f16(fbb, wfrag, zero, 0, 0, 0);
    floatx4 c4 = __builtin_amdgcn_mfma_f32_16x16x32_f16(fab, wfrag, zero, 0, 0, 0);
    #pragma unroll
    for (int i = 0; i < 4; ++i) {
        out[0][i] = (_Float16)c0[i];
        out[1][i] = (_Float16)c1[i];
        out[2][i] = (_Float16)c2[i];
        out[3][i] = (_Float16)c3[i];
        out[4][i] = (_Float16)c4[i];
    }
}

// write one position's held results as transposed h_T (region aliases the
// now-dead planes).
__device__ __forceinline__ void hwrite_pos(_Float16* __restrict__ sm,
                                           int p, int crow, const half4 out[5])
{
    int m0 = (p >> 1) << 4;
    int x0 = (p & 1) << 4;
    int cb = x0 * HTP + m0 + crow;
    #pragma unroll
    for (int q = 0; q < 5; ++q)
        *(half4*)&sm[cb + q * HTSZ] = out[q];
}

template <bool FUSE>
__global__ __launch_bounds__(256, 7) void ssim_mfma_kernel(
    const float* __restrict__ A, const float* __restrict__ B,
    int H, int W, float2* __restrict__ partial,
    float* __restrict__ poolA, float* __restrict__ poolB)
{
    __shared__ __align__(16) _Float16 sm[LDSH];   // 18944 B
    __shared__ float red[16];

    const float w[11] = GWLIST;
    const int tid  = threadIdx.x;
    const int lane = tid & 63;
    const int wv   = tid >> 6;
    const int gx0  = blockIdx.x * 32;
    const int gy0  = blockIdx.y * 32;
    const int z    = blockIdx.z;
    const float* a = A + (size_t)z * H * W;
    const float* b = B + (size_t)z * H * W;

    // ---- wave 0: build band-weight fragment table (64 lanes x half8) ----
    if (tid < 64) {
        int base = ((tid >> 4) << 3) - (tid & 15);
        half8 wf;
        #pragma unroll
        for (int i = 0; i < 8; ++i) {
            int j = base + i;
            float v = 0.f;
            #pragma unroll
            for (int J = 0; J < 11; ++J) v = (j == J) ? w[J] : v;
            wf[i] = (_Float16)v;
        }
        *(half8*)&sm[WT0 + tid * 8] = wf;
    }

    // ---- stage 1: 48x48 region -> 2 fp16 planes (a, b) ------------------
    const bool fast = (gy0 + 48 <= H) && (gx0 + 48 <= W);
    for (int e = tid; e < 288; e += 256) {        // 48 rows x 6 col-octets
        int r = e / 6, c8 = e - r * 6;
        float fa[8], fb[8];
        if (fast) {
            const float* pa = a + (size_t)(gy0 + r) * W + gx0 + c8 * 8;
            const float* pb = b + (size_t)(gy0 + r) * W + gx0 + c8 * 8;
            *(float4*)&fa[0] = *(const float4*)pa;
            *(float4*)&fa[4] = *(const float4*)(pa + 4);
            *(float4*)&fb[0] = *(const float4*)pb;
            *(float4*)&fb[4] = *(const float4*)(pb + 4);
        } else {
            int gy = gy0 + r;
            #pragma unroll
            for (int i = 0; i < 8; ++i) {
                int gx = gx0 + c8 * 8 + i;
                bool ok = (gy < H) && (gx < W);
                size_t idx = (size_t)gy * W + gx;
                fa[i] = ok ? a[idx] : 0.f;
                fb[i] = ok ? b[idx] : 0.f;
            }
        }
        half8 ha, hb;
        #pragma unroll
        for (int i = 0; i < 8; ++i) {
            ha[i] = (_Float16)fa[i];
            hb[i] = (_Float16)fb[i];
        }
        int o = r * PP + c8 * 8;
        *(half8*)&sm[o]       = ha;
        *(half8*)&sm[o + PSZ] = hb;
    }
    __syncthreads();                               // A: planes ready

    const half8 wfrag = *(const half8*)&sm[WT0 + lane * 8];

    // ---- stage 2a: h-conv, results held in registers --------------------
    // position p -> (m0 in {0,16,32}, x0 in {0,16}); waves 0-1 take 2
    // positions (wv, wv+4), waves 2-3 take 1 (wv).
    half4 r0[5], r1[5];
    const bool have1 = (wv < 2);
    {
        const int arow = (lane & 15) * PP + ((lane >> 4) << 3);
        hconv_pos(sm, wfrag, wv, arow, r0);
        if (have1) hconv_pos(sm, wfrag, wv + 4, arow, r1);
    }
    __syncthreads();                               // B: all plane reads done

    // ---- stage 2b: write h_T over the dead plane region -----------------
    {
        const int crow = (lane & 15) * HTP + ((lane >> 4) << 2);
        hwrite_pos(sm, wv, crow, r0);
        if (have1) hwrite_pos(sm, wv + 4, crow, r1);
    }
    __syncthreads();                               // C: h_T ready

    // ---- stage 3: v-conv via MFMA (one 16x16 subtile per wave) + SSIM ---
    float csSum = 0.f, ssimSum = 0.f;
    {
        const int y0 = (wv >> 1) << 4;
        const int x0 = (wv & 1) << 4;
        const int brow = (lane & 15) * HTP + ((lane >> 4) << 3);
        floatx4 m[5];
        #pragma unroll
        for (int q = 0; q < 5; ++q) {
            half8 bfrag = *(const half8*)&sm[q * HTSZ + x0 * HTP + y0 + brow];
            floatx4 c = {0.f, 0.f, 0.f, 0.f};
            m[q] = __builtin_amdgcn_mfma_f32_16x16x32_f16(wfrag, bfrag, c, 0, 0, 0);
        }
        const int OH = H - HALO, OW = W - HALO;
        const int gx  = gx0 + x0 + (lane & 15);
        const int gyb = gy0 + y0 + ((lane >> 4) << 2);
        const float C1 = 1e-4f;   // (0.01*1)^2
        const float C2 = 9e-4f;   // (0.03*1)^2
        if (gx < OW) {
            #pragma unroll
            for (int i = 0; i < 4; ++i) {
                int gy = gyb + i;
                if (gy < OH) {
                    float mu1 = m[0][i], mu2 = m[1][i];
                    float s1sq = m[2][i] - mu1 * mu1;
                    float s2sq = m[3][i] - mu2 * mu2;
                    float s12  = m[4][i] - mu1 * mu2;
                    float denom = s1sq + s2sq + C2;
                    float num   = 2.f * s12 + C2;
                    float csv = num * __frcp_rn(denom);
                    float ssv = csv * (2.f * mu1 * mu2 + C1) *
                                __frcp_rn(mu1 * mu1 + mu2 * mu2 + C1);
                    csSum   += csv;
                    ssimSum += ssv;
                }
            }
        }
    }

    // ---- block reduction -> per-block partial slot ----------------------
    #pragma unroll
    for (int off = 32; off > 0; off >>= 1) {
        csSum   += __shfl_down(csSum, off, 64);
        ssimSum += __shfl_down(ssimSum, off, 64);
    }
    if (lane == 0) {
        red[wv]     = csSum;
        red[8 + wv] = ssimSum;
    }
    __syncthreads();
    if (tid == 0) {
        float c = 0.f, s = 0.f;
        #pragma unroll
        for (int i = 0; i < 4; ++i) { c += red[i]; s += red[8 + i]; }
        int slot = (z * gridDim.y + blockIdx.y) * gridDim.x + blockIdx.x;
        partial[slot] = make_float2(c, s);
    }

    // ---- fused 2x2 avg-pool of this block's own 32x32 input region ------
    if (FUSE && tid < 128) {
        const int OH2 = H >> 1, OW2 = W >> 1;
        const int img = tid >> 6;            // 0 = A, 1 = B
        const int rem = tid & 63;
        const int pr  = rem >> 2;            // pooled row 0..15
        const int pq  = rem & 3;             // pooled float4-col 0..3
        const float* src = img ? b : a;
        float* dst = (img ? poolB : poolA) + (size_t)z * OH2 * OW2;
        size_t base = (size_t)(gy0 + 2 * pr) * W + gx0 + pq * 8;
        float4 r0v = *(const float4*)(src + base);
        float4 r1v = *(const float4*)(src + base + 4);
        float4 r2v = *(const float4*)(src + base + W);
        float4 r3v = *(const float4*)(src + base + W + 4);
        float4 o;
        o.x = 0.25f * (r0v.x + r0v.y + r2v.x + r2v.y);
        o.y = 0.25f * (r0v.z + r0v.w + r2v.z + r2v.w);
        o.z = 0.25f * (r1v.x + r1v.y + r3v.x + r3v.y);
        o.w = 0.25f * (r1v.z + r1v.w + r3v.z + r3v.w);
        *(float4*)(dst + (size_t)((gy0 >> 1) + pr) * OW2 + (gx0 >> 1) + pq * 4) = o;
    }
}

// ================= exact fp32 scalar kernel (scales 2-4) ===================
#define TH   32
#define ROWS (TH + HALO)      // 42
#define HSTR 32
#define HQ   (ROWS * HSTR)    // 1344 floats

template <bool FUSE>
__global__ __launch_bounds__(256, 5) void ssim_scalar_kernel(
    const float* __restrict__ A, const float* __restrict__ B,
    int H, int W, float2* __restrict__ partial,
    float* __restrict__ poolA, float* __restrict__ poolB)
{
    __shared__ __align__(16) float lds[5 * HQ];   // 26880 B
    __shared__ float red[16];

    const float w[11] = GWLIST;

    const int tid = threadIdx.x;
    const int gx0 = blockIdx.x * 32;
    const int gy0 = blockIdx.y * TH;
    const int z   = blockIdx.z;
    const float* a = A + (size_t)z * H * W;
    const float* b = B + (size_t)z * H * W;

    const bool fast = (gy0 + ROWS <= H) && (gx0 + 44 <= W);
    for (int e = tid; e < ROWS * 8; e += 256) {
        int r = e >> 3, c0 = (e & 7) * 4;
        int gy = gy0 + r;
        float s1[4]  = {0.f, 0.f, 0.f, 0.f};
        float s2[4]  = {0.f, 0.f, 0.f, 0.f};
        float s11[4] = {0.f, 0.f, 0.f, 0.f};
        float s22[4] = {0.f, 0.f, 0.f, 0.f};
        float s12[4] = {0.f, 0.f, 0.f, 0.f};
        #pragma unroll
        for (int c = 0; c < 4; ++c) {
            float ea[4], eb[4];
            if (fast) {
                const float* pa = a + (size_t)gy * W + gx0 + c0 + 4 * c;
                const float* pb = b + (size_t)gy * W + gx0 + c0 + 4 * c;
                *(float4*)&ea[0] = *(const float4*)pa;
                *(float4*)&eb[0] = *(const float4*)pb;
            } else {
                #pragma unroll
                for (int t = 0; t < 4; ++t) {
                    int gx = gx0 + c0 + 4 * c + t;
                    bool ok = (gy < H) && (gx < W);
                    size_t idx = (size_t)gy * W + gx;
                    ea[t] = ok ? a[idx] : 0.f;
                    eb[t] = ok ? b[idx] : 0.f;
                }
            }
            #pragma unroll
            for (int mm = 0; mm < 4; ++mm) {
                const int i = 4 * c + mm;
                float va = ea[mm], vb = eb[mm];
                float vaa = va * va, vbb = vb * vb, vab = va * vb;
                #pragma unroll
                for (int k = 0; k < 4; ++k) {
                    const int j = i - k;
                    if (j >= 0 && j <= 10) {
                        float wj = w[j];
                        s1[k]  += wj * va;
                        s2[k]  += wj * vb;
                        s11[k] += wj * vaa;
                        s22[k] += wj * vbb;
                        s12[k] += wj * vab;
                    }
                }
            }
        }
        int hb = r * HSTR + c0;
        *(float4*)&lds[hb + 0 * HQ] = make_float4(s1[0],  s1[1],  s1[2],  s1[3]);
        *(float4*)&lds[hb + 1 * HQ] = make_float4(s2[0],  s2[1],  s2[2],  s2[3]);
        *(float4*)&lds[hb + 2 * HQ] = make_float4(s11[0], s11[1], s11[2], s11[3]);
        *(float4*)&lds[hb + 3 * HQ] = make_float4(s22[0], s22[1], s22[2], s22[3]);
        *(float4*)&lds[hb + 4 * HQ] = make_float4(s12[0], s12[1], s12[2], s12[3]);
    }
    __syncthreads();

    const float C1 = 1e-4f;
    const float C2 = 9e-4f;
    float csSum = 0.f, ssimSum = 0.f;
    {
        const int ox  = tid & 31;
        const int oy0 = (tid >> 5) * 4;
        float m[5][4];
        #pragma unroll
        for (int q = 0; q < 5; ++q) {
            const float* hq = &lds[q * HQ + oy0 * HSTR + ox];
            float win[14];
            #pragma unroll
            for (int i = 0; i < 14; ++i) win[i] = hq[i * HSTR];
            #pragma unroll
            for (int k = 0; k < 4; ++k) {
                float acc = 0.f;
                #pragma unroll
                for (int j = 0; j < 11; ++j) acc += w[j] * win[k + j];
                m[q][k] = acc;
            }
        }
        const int OH = H - HALO, OW = W - HALO;
        const int gx = gx0 + ox;
        #pragma unroll
        for (int k = 0; k < 4; ++k) {
            int gy = gy0 + oy0 + k;
            if (gy < OH && gx < OW) {
                float mu1 = m[0][k], mu2 = m[1][k];
                float s1sq = m[2][k] - mu1 * mu1;
                float s2sq = m[3][k] - mu2 * mu2;
                float s12  = m[4][k] - mu1 * mu2;
                float denom  = s1sq + s2sq + C2;
                float num_cs = 2.f * s12 + C2;
                float csv = num_cs * __frcp_rn(denom);
                float ssv = csv * (2.f * mu1 * mu2 + C1) *
                            __frcp_rn(mu1 * mu1 + mu2 * mu2 + C1);
                csSum   += csv;
                ssimSum += ssv;
            }
        }
    }

    #pragma unroll
    for (int off = 32; off > 0; off >>= 1) {
        csSum   += __shfl_down(csSum, off, 64);
        ssimSum += __shfl_down(ssimSum, off, 64);
    }
    int wave = tid >> 6, lane = tid & 63;
    if (lane == 0) {
        red[wave]     = csSum;
        red[8 + wave] = ssimSum;
    }
    __syncthreads();
    if (tid == 0) {
        float c = 0.f, s = 0.f;
        #pragma unroll
        for (int i = 0; i < 4; ++i) { c += red[i]; s += red[8 + i]; }
        int slot = (z * gridDim.y + blockIdx.y) * gridDim.x + blockIdx.x;
        partial[slot] = make_float2(c, s);
    }

    if (FUSE && tid < 128) {
        const int OH2 = H >> 1, OW2 = W >> 1;
        const int img = tid >> 6;
        const int rem = tid & 63;
        const int pr  = rem >> 2;
        const int pq  = rem & 3;
        const float* src = img ? b : a;
        float* dst = (img ? poolB : poolA) + (size_t)z * OH2 * OW2;
        size_t base = (size_t)(gy0 + 2 * pr) * W + gx0 + pq * 8;
        float4 r0 = *(const float4*)(src + base);
        float4 r1 = *(const float4*)(src + base + 4);
        float4 r2 = *(const float4*)(src + base + W);
        float4 r3 = *(const float4*)(src + base + W + 4);
        float4 o;
        o.x = 0.25f * (r0.x + r0.y + r2.x + r2.y);
        o.y = 0.25f * (r0.z + r0.w + r2.z + r2.w);
        o.z = 0.25f * (r1.x + r1.y + r3.x + r3.y);
        o.w = 0.25f * (r1.z + r1.w + r3.z + r3.w);
        *(float4*)(dst + (size_t)((gy0 >> 1) + pr) * OW2 + (gx0 >> 1) + pq * 4) = o;
    }
}

// ---------------------------------------------------------------------------
// Reduce all per-block partials (5 segments) and combine.
__global__ void final_kernel(const float2* __restrict__ partial, float* __restrict__ out) {
    __shared__ double red[8];
    __shared__ double resC[5], resS[5];
    const int segs[6] = {0, 12288, 15360, 16128, 16320, 16368};
    const int tid = threadIdx.x;
    for (int s = 0; s < 5; ++s) {
        double c = 0.0, v = 0.0;
        #pragma unroll 4
        for (int i = segs[s] + tid; i < segs[s + 1]; i += 256) {
            float2 p = partial[i];
            c += (double)p.x;
            v += (double)p.y;
        }
        #pragma unroll
        for (int off = 32; off > 0; off >>= 1) {
            c += __shfl_down(c, off, 64);
            v += __shfl_down(v, off, 64);
        }
        int wave = tid >> 6, lane = tid & 63;
        __syncthreads();
        if (lane == 0) { red[wave] = c; red[4 + wave] = v; }
        __syncthreads();
        if (tid == 0) {
            resC[s] = red[0] + red[1] + red[2] + red[3];
            resS[s] = red[4] + red[5] + red[6] + red[7];
        }
    }
    __syncthreads();
    if (tid == 0) {
        const double wgt[5] = {0.0448, 0.2856, 0.3001, 0.2363, 0.1333};
        double ms = 1.0;
        for (int s = 0; s < 5; ++s) {
            int Hs = 512 >> s;
            double cnt = (double)NIMG * (double)(Hs - 10) * (double)(Hs - 10);
            double cs = resC[s] / cnt;
            double sv = resS[s] / cnt;
            if (cs < 0.0) cs = 0.0;
            if (sv < 0.0) sv = 0.0;
            cs = (cs + 1.0) * 0.5;
            sv = (sv + 1.0) * 0.5;
            ms *= pow((s < 4) ? cs : sv, wgt[s]);
        }
        out[0] = (float)(1.0 - ms);
    }
}

// ---------------------------------------------------------------------------
extern "C" void kernel_launch(void* const* d_in, const int* in_sizes, int n_in,
                              void* d_out, int out_size, void* d_ws, size_t ws_size,
                              hipStream_t stream) {
    (void)in_sizes; (void)n_in; (void)out_size; (void)ws_size;
    const float* A0 = (const float*)d_in[0];
    const float* B0 = (const float*)d_in[1];
    float* out = (float*)d_out;

    char* ws = (char*)d_ws;
    float2* partial = (float2*)ws;             // 16368 float2 = 131 KB
    float* pyr = (float*)(ws + (1 << 18));     // 256 KB offset

    float* pa[5] = {nullptr, nullptr, nullptr, nullptr, nullptr};
    float* pb[5] = {nullptr, nullptr, nullptr, nullptr, nullptr};
    size_t off = 0;
    for (int s = 1; s <= 4; ++s) {
        int Hs = 512 >> s;
        size_t n = (size_t)NIMG * Hs * Hs;
        pa[s] = pyr + off; off += n;
        pb[s] = pyr + off; off += n;
    }

    const int segs[5] = {0, 12288, 15360, 16128, 16320};

    const float* curA = A0;
    const float* curB = B0;
    for (int s = 0; s < 5; ++s) {
        int Hs = 512 >> s;
        int g  = Hs >> 5;                      // tiles exactly cover image
        dim3 grid(g, g, NIMG);
        if (s < 2) {
            ssim_mfma_kernel<true><<<grid, 256, 0, stream>>>(
                curA, curB, Hs, Hs, partial + segs[s], pa[s + 1], pb[s + 1]);
            curA = pa[s + 1];
            curB = pb[s + 1];
        } else if (s < 4) {
            ssim_scalar_kernel<true><<<grid, 256, 0, stream>>>(
                curA, curB, Hs, Hs, partial + segs[s], pa[s + 1], pb[s + 1]);
            curA = pa[s + 1];
            curB = pb[s + 1];
        } else {
            ssim_scalar_kernel<false><<<grid, 256, 0, stream>>>(
                curA, curB, Hs, Hs, partial + segs[s], nullptr, nullptr);
        }
    }

    final_kernel<<<1, 256, 0, stream>>>(partial, out);
}